// Round 15
// baseline (520.926 us; speedup 1.0000x reference)
//
#include <hip/hip_runtime.h>
#include <hip/hip_fp16.h>
#include <cstddef>
#include <cstdint>

#define N_NODES   100000
#define N_EDGES   1600000
#define N_GRAPHS  512
#define HIDDEN    128
#define N_LAYERS  3

#define N_WIN        400
#define WIN_NODES    (N_NODES / N_WIN)      // 250
#define PLACE_BLOCKS 128
#define PCHUNK       (N_EDGES / PLACE_BLOCKS)  // 12500

#define F2H_BLOCKS   ((N_NODES * HIDDEN / 8) / 256)            // 6250
#define WCONV_BLOCKS (N_LAYERS * 2 * 16)                       // 96
#define GB_BLOCKS    2
#define PREPC_BLOCKS (PLACE_BLOCKS + F2H_BLOCKS + WCONV_BLOCKS + GB_BLOCKS)

typedef _Float16 half8  __attribute__((ext_vector_type(8)));
typedef _Float16 half4v __attribute__((ext_vector_type(4)));
typedef _Float16 half2v __attribute__((ext_vector_type(2)));
typedef float    floatx4 __attribute__((ext_vector_type(4)));
typedef float    floatx2 __attribute__((ext_vector_type(2)));

// ---------------------------------------------------------------------------
// fused prep + win_count (R13/R14-confirmed). Emits fp8 twin of X only.
// ---------------------------------------------------------------------------
__global__ __launch_bounds__(256) void prep_count_kernel(const float* __restrict__ X,
                                                         unsigned char* __restrict__ outq,
                                                         const float* __restrict__ w1,
                                                         const float* __restrict__ w2,
                                                         __half* __restrict__ wt1,
                                                         __half* __restrict__ wt2,
                                                         const int* __restrict__ batch,
                                                         int* __restrict__ gstart,
                                                         const int* __restrict__ dst,
                                                         int* __restrict__ counts) {
    __shared__ float tile[32][33];
    __shared__ int   cs[N_WIN];
    const int b = blockIdx.x;
    if (b < PLACE_BLOCKS) {
        for (int i = threadIdx.x; i < N_WIN; i += 256) cs[i] = 0;
        __syncthreads();
        const int4* d4 = (const int4*)(dst + b * PCHUNK);
        for (int i = threadIdx.x; i < PCHUNK / 4; i += 256) {
            int4 d = d4[i];
            atomicAdd(&cs[d.x / WIN_NODES], 1);
            atomicAdd(&cs[d.y / WIN_NODES], 1);
            atomicAdd(&cs[d.z / WIN_NODES], 1);
            atomicAdd(&cs[d.w / WIN_NODES], 1);
        }
        __syncthreads();
        for (int i = threadIdx.x; i < N_WIN; i += 256)
            counts[i * PLACE_BLOCKS + b] = cs[i];
    } else if (b < PLACE_BLOCKS + F2H_BLOCKS) {
        int t = (b - PLACE_BLOCKS) * 256 + threadIdx.x;
        const float4* in4 = (const float4*)X;
        float4 a = in4[t * 2 + 0];
        float4 c = in4[t * 2 + 1];
        unsigned r0 = 0, r1 = 0;
        r0 = __builtin_amdgcn_cvt_pk_fp8_f32(a.x, a.y, r0, false);
        r0 = __builtin_amdgcn_cvt_pk_fp8_f32(a.z, a.w, r0, true);
        r1 = __builtin_amdgcn_cvt_pk_fp8_f32(c.x, c.y, r1, false);
        r1 = __builtin_amdgcn_cvt_pk_fp8_f32(c.z, c.w, r1, true);
        ((uint2*)outq)[t] = make_uint2(r0, r1);
    } else if (b < PLACE_BLOCKS + F2H_BLOCKS + WCONV_BLOCKS) {
        const int bb = b - PLACE_BLOCKS - F2H_BLOCKS;
        const int mat = bb & 1;
        const int tt = (bb >> 1) & 15;
        const int l  = bb >> 5;
        const int ti = (tt >> 2) * 32, tj = (tt & 3) * 32;
        const float* W = (mat ? w2 : w1) + (size_t)l * HIDDEN * HIDDEN;
        __half* WT = (mat ? wt2 : wt1) + (size_t)l * HIDDEN * HIDDEN;
        const int r = threadIdx.x >> 5;
        const int c = threadIdx.x & 31;
#pragma unroll
        for (int rr = 0; rr < 4; ++rr)
            tile[r + 8 * rr][c] = W[(size_t)(ti + r + 8 * rr) * HIDDEN + tj + c];
        __syncthreads();
#pragma unroll
        for (int rr = 0; rr < 4; ++rr)
            WT[(size_t)(tj + r + 8 * rr) * HIDDEN + ti + c] =
                __float2half(tile[c][r + 8 * rr]);
    } else {
        const int g = (b - PLACE_BLOCKS - F2H_BLOCKS - WCONV_BLOCKS) * 256 + threadIdx.x;
        if (g < N_GRAPHS) {
            int lo = 0, hi = N_NODES;
            while (lo < hi) {
                int mid = (lo + hi) >> 1;
                if (batch[mid] < g) lo = mid + 1; else hi = mid;
            }
            gstart[g] = lo;
        }
        if (g == 0) gstart[N_GRAPHS] = N_NODES;
    }
}

// place (R13-confirmed: absorbs win_scan1)
__global__ __launch_bounds__(512) void win_place_kernel(const int* __restrict__ src,
                                                        const int* __restrict__ dst,
                                                        const int* __restrict__ counts,
                                                        int* __restrict__ colsum,
                                                        int2* __restrict__ wedge) {
    __shared__ int ws[512];
    __shared__ int off[N_WIN];
    const int t = threadIdx.x;
    const int b = blockIdx.x;

    int total = 0, part = 0;
    if (t < N_WIN) {
        const int* col = counts + t * PLACE_BLOCKS;
#pragma unroll 4
        for (int bb = 0; bb < PLACE_BLOCKS; ++bb) {
            int v = col[bb];
            total += v;
            if (bb < b) part += v;
        }
        if (b == 0) colsum[t] = total;
    }
    ws[t] = (t < N_WIN) ? total : 0;
    __syncthreads();
#pragma unroll
    for (int o = 1; o < 512; o <<= 1) {
        int u = (t >= o) ? ws[t - o] : 0;
        __syncthreads();
        ws[t] += u;
        __syncthreads();
    }
    if (t < N_WIN) off[t] = part + ((t == 0) ? 0 : ws[t - 1]);
    __syncthreads();
    const int4* d4 = (const int4*)(dst + b * PCHUNK);
    const int4* s4 = (const int4*)(src + b * PCHUNK);
    for (int i = t; i < PCHUNK / 4; i += 512) {
        int4 d = d4[i];
        int4 s = s4[i];
        int p0 = atomicAdd(&off[d.x / WIN_NODES], 1); wedge[p0] = make_int2(d.x, s.x);
        int p1 = atomicAdd(&off[d.y / WIN_NODES], 1); wedge[p1] = make_int2(d.y, s.y);
        int p2 = atomicAdd(&off[d.z / WIN_NODES], 1); wedge[p2] = make_int2(d.z, s.z);
        int p3 = atomicAdd(&off[d.w / WIN_NODES], 1); wedge[p3] = make_int2(d.w, s.w);
    }
}

// fused per-window CSR
__global__ __launch_bounds__(512) void win_csr_kernel(const int2* __restrict__ wedge,
                                                      const int* __restrict__ colsum,
                                                      int* __restrict__ row_ptr,
                                                      int* __restrict__ csr_src) {
    __shared__ int ws[512];
    __shared__ int cnt[WIN_NODES];
    __shared__ int bb[2];
    const int w = blockIdx.x, n0 = w * WIN_NODES, t = threadIdx.x;
    ws[t] = (t < N_WIN) ? colsum[t] : 0;
    __syncthreads();
#pragma unroll
    for (int o = 1; o < 512; o <<= 1) {
        int u = (t >= o) ? ws[t - o] : 0;
        __syncthreads();
        ws[t] += u;
        __syncthreads();
    }
    if (t == 0) { bb[0] = (w > 0) ? ws[w - 1] : 0; bb[1] = ws[w]; }
    if (w == N_WIN - 1 && t == 0) row_ptr[N_NODES] = ws[N_WIN - 1];
    for (int i = t; i < WIN_NODES; i += 512) cnt[i] = 0;
    __syncthreads();
    const int b0 = bb[0], b1 = bb[1];
    for (int e = b0 + t; e < b1; e += 512)
        atomicAdd(&cnt[wedge[e].x - n0], 1);
    __syncthreads();
    ws[t] = (t < WIN_NODES) ? cnt[t] : 0;
    __syncthreads();
#pragma unroll
    for (int o = 1; o < 512; o <<= 1) {
        int u = (t >= o) ? ws[t - o] : 0;
        __syncthreads();
        ws[t] += u;
        __syncthreads();
    }
    const int excl = (t == 0) ? 0 : ws[t - 1];
    if (t < WIN_NODES) {
        row_ptr[n0 + t] = b0 + excl;
        cnt[t] = b0 + excl;
    }
    __syncthreads();
    for (int e = b0 + t; e < b1; e += 512) {
        int2 ed = wedge[e];
        int p = atomicAdd(&cnt[ed.x - n0], 1);
        csr_src[p] = ed.y;
    }
}

// ---------------------------------------------------------------------------
// gather core (R14-confirmed: fp8 self-feature, packed floatx2 accumulate).
// R15: epilogue writes the z row into a SWIZZLED LDS tile (chunk c of row r
// stored at chunk c^r) instead of global -- the zh handoff (51.2 MB/layer of
// cross-XCD dirty-L2 traffic) is eliminated.
// ---------------------------------------------------------------------------
__device__ __forceinline__ void acc_fp8x16(floatx2* acc, uint4 v) {
    acc[0] += __builtin_amdgcn_cvt_pk_f32_fp8(v.x, false);
    acc[1] += __builtin_amdgcn_cvt_pk_f32_fp8(v.x, true);
    acc[2] += __builtin_amdgcn_cvt_pk_f32_fp8(v.y, false);
    acc[3] += __builtin_amdgcn_cvt_pk_f32_fp8(v.y, true);
    acc[4] += __builtin_amdgcn_cvt_pk_f32_fp8(v.z, false);
    acc[5] += __builtin_amdgcn_cvt_pk_f32_fp8(v.z, true);
    acc[6] += __builtin_amdgcn_cvt_pk_f32_fp8(v.w, false);
    acc[7] += __builtin_amdgcn_cvt_pk_f32_fp8(v.w, true);
}

__device__ __forceinline__ void gather_node_lds(int node, int lane,
                                                const unsigned char* __restrict__ Xq,
                                                const int* __restrict__ row_ptr,
                                                const int* __restrict__ csr_src,
                                                _Float16* __restrict__ ztrow, int row) {
    const int grp = lane >> 3;     // 0..7 neighbor group
    const int gm  = lane & 7;      // 0..7 col group (16 cols each)
    const uint4* Q = (const uint4*)Xq;

    floatx2 acc[8];
#pragma unroll
    for (int j = 0; j < 8; ++j) acc[j] = floatx2{0.f, 0.f};

    if (grp == 0) {   // self feature as one extra fp8 neighbor
        uint4 v = Q[(size_t)node * 8 + gm];
        acc_fp8x16(acc, v);
    }

    int k = row_ptr[node];
    const int end = row_ptr[node + 1];

    for (; k + 16 <= end; k += 16) {
        int n0 = csr_src[k + grp];
        int n1 = csr_src[k + 8 + grp];
        uint4 v0 = Q[(size_t)n0 * 8 + gm];
        uint4 v1 = Q[(size_t)n1 * 8 + gm];
        acc_fp8x16(acc, v0);
        acc_fp8x16(acc, v1);
    }
    if (k + 8 <= end) {
        int n0 = csr_src[k + grp];
        uint4 v0 = Q[(size_t)n0 * 8 + gm];
        acc_fp8x16(acc, v0);
        k += 8;
    }
    int rem = end - k;
    if (grp < rem) {
        int n0 = csr_src[k + grp];
        uint4 v0 = Q[(size_t)n0 * 8 + gm];
        acc_fp8x16(acc, v0);
    }

    half2v hh[8];
#pragma unroll
    for (int j = 0; j < 8; ++j) {
        hh[j][0] = (_Float16)acc[j][0];
        hh[j][1] = (_Float16)acc[j][1];
    }
#pragma unroll
    for (int j = 0; j < 8; ++j) {
        int b = __shfl_xor(__builtin_bit_cast(int, hh[j]), 8);
        hh[j] = hh[j] + __builtin_bit_cast(half2v, b);
    }
#pragma unroll
    for (int j = 0; j < 8; ++j) {
        int b = __shfl_xor(__builtin_bit_cast(int, hh[j]), 16);
        hh[j] = hh[j] + __builtin_bit_cast(half2v, b);
    }
#pragma unroll
    for (int j = 0; j < 8; ++j) {
        int b = __shfl_xor(__builtin_bit_cast(int, hh[j]), 32);
        hh[j] = hh[j] + __builtin_bit_cast(half2v, b);
    }

    if (grp == 0) {
        half8 o0, o1;
#pragma unroll
        for (int j = 0; j < 4; ++j) { o0[2 * j] = hh[j][0]; o0[2 * j + 1] = hh[j][1]; }
#pragma unroll
        for (int j = 0; j < 4; ++j) { o1[2 * j] = hh[4 + j][0]; o1[2 * j + 1] = hh[4 + j][1]; }
        // cols 16gm..16gm+7 -> chunk 2gm; 16gm+8..15 -> chunk 2gm+1; XOR-swizzled by row
        *(half8*)&ztrow[((2 * gm) ^ row) << 3]     = o0;
        *(half8*)&ztrow[((2 * gm + 1) ^ row) << 3] = o1;
    }
}

// ---------------------------------------------------------------------------
// 512-thread pool body (for the fused dispatch). Atomic-free segment sum.
// ---------------------------------------------------------------------------
__device__ __forceinline__ void gpool_body512(int g,
                                              const __half* __restrict__ H,
                                              const int* __restrict__ gstart,
                                              float* __restrict__ pooled, int layer) {
    __shared__ float red[32][16][8];   // 16 KiB
    const int f8 = threadIdx.x & 15;
    const int qt = threadIdx.x >> 4;   // 0..31
    const int s = gstart[g], e = gstart[g + 1];

    float acc[8];
#pragma unroll
    for (int j = 0; j < 8; ++j) acc[j] = 0.f;
    for (int n = s + qt; n < e; n += 32) {
        half8 v = ((const half8*)(H + (size_t)n * HIDDEN))[f8];
#pragma unroll
        for (int j = 0; j < 8; ++j) acc[j] += (float)v[j];
    }
#pragma unroll
    for (int j = 0; j < 8; ++j) red[qt][f8][j] = acc[j];
    __syncthreads();
    if (threadIdx.x < 128) {
        const int c = threadIdx.x;
        float sum = 0.f;
#pragma unroll
        for (int p = 0; p < 32; ++p) sum += red[p][c >> 3][c & 7];
        pooled[(size_t)g * (HIDDEN * N_LAYERS) + layer * HIDDEN + c] = sum;
    }
}

// ---------------------------------------------------------------------------
// Fused gather + MLP (R15). Per 16-node tile: 8 waves each gather 2 nodes
// (proven gather core) into a swizzled LDS z-tile; then the R12-proven
// wave-split MLP consumes it from LDS. zh never touches global memory.
// Pool(prev layer) rides as grid-split blocks (prev_layer >= 0).
// Raw lgkm-only barriers (R12): vmcnt never drained; dbuf on zt and hs.
// ---------------------------------------------------------------------------
#define POOL_BLKS N_GRAPHS   // 512
#define GM_BLOCKS 1024
__global__ __launch_bounds__(512, 4) void gather_mlp_kernel(
        const unsigned char* __restrict__ Xq,
        const __half* __restrict__ Hpool,
        const int* __restrict__ row_ptr,
        const int* __restrict__ csr_src,
        const __half* __restrict__ Wt1,
        const __half* __restrict__ Wt2,
        const float* __restrict__ b1,
        const float* __restrict__ b2,
        const int* __restrict__ gstart,
        float* __restrict__ pooled,
        int prev_layer,
        __half* __restrict__ C16,
        unsigned char* __restrict__ Q8) {
    __shared__ _Float16 zt[2][16][128];   // 8 KiB, swizzled z tiles (dbuf)
    __shared__ _Float16 hs[2][16][128];   // 8 KiB, swizzled h tiles (dbuf)

    const bool has_pool = (prev_layer >= 0);
    if (has_pool && blockIdx.x < POOL_BLKS) {
        gpool_body512(blockIdx.x, Hpool, gstart, pooled, prev_layer);
        return;
    }
    const int gb = blockIdx.x - (has_pool ? POOL_BLKS : 0);

    const int tid  = threadIdx.x;
    const int wv   = tid >> 6;         // 0..7
    const int lane = tid & 63;
    const int m    = lane & 15;
    const int q    = lane >> 4;
    const int NTILES = N_NODES / 16;   // 6250

    // per-wave weight slices + biases (register-resident)
    half8 wf1[4], wf2[4];
    float bl1[4], bl2[4];
    {
        const half8* W1row = (const half8*)(Wt1 + (size_t)(wv * 16 + m) * HIDDEN);
        const half8* W2row = (const half8*)(Wt2 + (size_t)(wv * 16 + m) * HIDDEN);
#pragma unroll
        for (int c = 0; c < 4; ++c) { wf1[c] = W1row[c * 4 + q]; wf2[c] = W2row[c * 4 + q]; }
#pragma unroll
        for (int r = 0; r < 4; ++r) {
            bl1[r] = b1[wv * 16 + q * 4 + r];
            bl2[r] = b2[wv * 16 + q * 4 + r];
        }
    }

    int buf = 0;
    for (int t = gb; t < NTILES; t += GM_BLOCKS) {
        // ---- gather phase: wave wv fills rows 2wv, 2wv+1 of zt[buf]
#pragma unroll
        for (int s = 0; s < 2; ++s) {
            const int row = 2 * wv + s;
            gather_node_lds(t * 16 + row, lane, Xq, row_ptr, csr_src,
                            &zt[buf][row][0], row);
        }
        __builtin_amdgcn_sched_barrier(0);
        asm volatile("s_waitcnt lgkmcnt(0)" ::: "memory");
        __builtin_amdgcn_s_barrier();
        __builtin_amdgcn_sched_barrier(0);

        // ---- mm1: h(:, wv-slice) = relu(z @ W1 + b1) -> swizzled hs[buf]
        {
            const _Float16* ar = &zt[buf][m][0];
            half8 a0 = *(const half8*)(ar + (((0 + q) ^ m) << 3));
            half8 a1 = *(const half8*)(ar + (((4 + q) ^ m) << 3));
            half8 a2 = *(const half8*)(ar + (((8 + q) ^ m) << 3));
            half8 a3 = *(const half8*)(ar + (((12 + q) ^ m) << 3));
            floatx4 acc = {0.f, 0.f, 0.f, 0.f};
            acc = __builtin_amdgcn_mfma_f32_16x16x32_f16(wf1[0], a0, acc, 0, 0, 0);
            acc = __builtin_amdgcn_mfma_f32_16x16x32_f16(wf1[1], a1, acc, 0, 0, 0);
            acc = __builtin_amdgcn_mfma_f32_16x16x32_f16(wf1[2], a2, acc, 0, 0, 0);
            acc = __builtin_amdgcn_mfma_f32_16x16x32_f16(wf1[3], a3, acc, 0, 0, 0);
            half4v o;
#pragma unroll
            for (int r = 0; r < 4; ++r) o[r] = (_Float16)fmaxf(acc[r] + bl1[r], 0.f);
            *(half4v*)&hs[buf][m][(((2 * wv + (q >> 1)) ^ m) << 3) + ((q & 1) << 2)] = o;
        }
        __builtin_amdgcn_sched_barrier(0);
        asm volatile("s_waitcnt lgkmcnt(0)" ::: "memory");
        __builtin_amdgcn_s_barrier();
        __builtin_amdgcn_sched_barrier(0);

        // ---- mm2: out = relu(h @ W2 + b2) -> fp16 + optional fp8
        {
            const _Float16* hr = &hs[buf][m][0];
            half8 h0 = *(const half8*)(hr + (((0 + q) ^ m) << 3));
            half8 h1 = *(const half8*)(hr + (((4 + q) ^ m) << 3));
            half8 h2 = *(const half8*)(hr + (((8 + q) ^ m) << 3));
            half8 h3 = *(const half8*)(hr + (((12 + q) ^ m) << 3));
            floatx4 acc = {0.f, 0.f, 0.f, 0.f};
            acc = __builtin_amdgcn_mfma_f32_16x16x32_f16(wf2[0], h0, acc, 0, 0, 0);
            acc = __builtin_amdgcn_mfma_f32_16x16x32_f16(wf2[1], h1, acc, 0, 0, 0);
            acc = __builtin_amdgcn_mfma_f32_16x16x32_f16(wf2[2], h2, acc, 0, 0, 0);
            acc = __builtin_amdgcn_mfma_f32_16x16x32_f16(wf2[3], h3, acc, 0, 0, 0);
            float v0 = fmaxf(acc[0] + bl2[0], 0.f);
            float v1 = fmaxf(acc[1] + bl2[1], 0.f);
            float v2 = fmaxf(acc[2] + bl2[2], 0.f);
            float v3 = fmaxf(acc[3] + bl2[3], 0.f);
            const size_t base = (size_t)(t * 16 + m) * HIDDEN + wv * 16 + q * 4;
            half4v o;
            o[0] = (_Float16)v0; o[1] = (_Float16)v1;
            o[2] = (_Float16)v2; o[3] = (_Float16)v3;
            *(half4v*)(C16 + base) = o;
            if (Q8) {
                unsigned r0 = 0;
                r0 = __builtin_amdgcn_cvt_pk_fp8_f32(v0, v1, r0, false);
                r0 = __builtin_amdgcn_cvt_pk_fp8_f32(v2, v3, r0, true);
                *(unsigned*)(Q8 + base) = r0;
            }
        }
        buf ^= 1;
    }
}

// ---------------------------------------------------------------------------
// Fused final gpool(layer 2) + classifier (R13-confirmed).
// ---------------------------------------------------------------------------
__global__ __launch_bounds__(256) void gpool_cls_kernel(const __half* __restrict__ Xh,
                                                        const int* __restrict__ gstart,
                                                        const float* __restrict__ pooled,
                                                        const float* __restrict__ w1,
                                                        const float* __restrict__ b1,
                                                        const float* __restrict__ w2,
                                                        const float* __restrict__ b2,
                                                        const float* __restrict__ w3,
                                                        const float* __restrict__ b3,
                                                        float* __restrict__ out) {
    __shared__ float red[16][16][8];
    __shared__ float hin[HIDDEN * N_LAYERS];
    __shared__ float h1v[HIDDEN];
    __shared__ float redc[HIDDEN];
    const int g   = blockIdx.x;
    const int tid = threadIdx.x;
    const int f8  = tid & 15;
    const int qt  = tid >> 4;
    const int s = gstart[g], e = gstart[g + 1];

    for (int i = tid; i < 2 * HIDDEN; i += 256)
        hin[i] = pooled[(size_t)g * (HIDDEN * N_LAYERS) + i];

    float acc[8];
#pragma unroll
    for (int j = 0; j < 8; ++j) acc[j] = 0.f;
    for (int n = s + qt; n < e; n += 16) {
        half8 v = ((const half8*)(Xh + (size_t)n * HIDDEN))[f8];
#pragma unroll
        for (int j = 0; j < 8; ++j) acc[j] += (float)v[j];
    }
#pragma unroll
    for (int j = 0; j < 8; ++j) red[qt][f8][j] = acc[j];
    __syncthreads();
    if (tid < 128) {
        float sum = 0.f;
#pragma unroll
        for (int p = 0; p < 16; ++p) sum += red[p][tid >> 3][tid & 7];
        hin[2 * HIDDEN + tid] = sum;
    }
    __syncthreads();

    if (tid < 128) {
        float sacc = 0.f;
        for (int k = 0; k < HIDDEN * N_LAYERS; ++k)
            sacc += hin[k] * w1[(size_t)k * HIDDEN + tid];
        h1v[tid] = fmaxf(sacc + b1[tid], 0.f);
    }
    __syncthreads();
    if (tid < 128) {
        float s2 = 0.f;
        for (int k = 0; k < HIDDEN; ++k) s2 += h1v[k] * w2[(size_t)k * HIDDEN + tid];
        s2 = fmaxf(s2 + b2[tid], 0.f);
        redc[tid] = s2 * w3[tid];
    }
    __syncthreads();
    for (int off = 64; off > 0; off >>= 1) {
        if (tid < off) redc[tid] += redc[tid + off];
        __syncthreads();
    }
    if (tid == 0) out[g] = redc[0] + b3[0];
}

// ---------------------------------------------------------------------------
extern "C" void kernel_launch(void* const* d_in, const int* in_sizes, int n_in,
                              void* d_out, int out_size, void* d_ws, size_t ws_size,
                              hipStream_t stream) {
    const float* X     = (const float*)d_in[0];
    const int*   ei    = (const int*)d_in[1];
    const int*   batch = (const int*)d_in[2];
    const float* w1all = (const float*)d_in[3];
    const float* b1all = (const float*)d_in[4];
    const float* w2all = (const float*)d_in[5];
    const float* b2all = (const float*)d_in[6];
    const float* cw1   = (const float*)d_in[7];
    const float* cb1   = (const float*)d_in[8];
    const float* cw2   = (const float*)d_in[9];
    const float* cb2   = (const float*)d_in[10];
    const float* cw3   = (const float*)d_in[11];
    const float* cb3   = (const float*)d_in[12];
    float* out = (float*)d_out;

    const int* src = ei;
    const int* dst = ei + N_EDGES;

    char* p = (char*)d_ws;
    auto alloc2 = [&](size_t bytes) {
        char* r = p;
        p += (bytes + 255) & ~(size_t)255;
        return r;
    };
    __half* hA      = (__half*)alloc2((size_t)N_NODES * HIDDEN * sizeof(__half));
    __half* hB      = (__half*)alloc2((size_t)N_NODES * HIDDEN * sizeof(__half));
    unsigned char* qA = (unsigned char*)alloc2((size_t)N_NODES * HIDDEN);
    unsigned char* qB = (unsigned char*)alloc2((size_t)N_NODES * HIDDEN);
    __half* wt1     = (__half*)alloc2((size_t)N_LAYERS * HIDDEN * HIDDEN * sizeof(__half));
    __half* wt2     = (__half*)alloc2((size_t)N_LAYERS * HIDDEN * HIDDEN * sizeof(__half));
    int2*   wedge   = (int2*)alloc2((size_t)N_EDGES * sizeof(int2));
    int*    csr     = (int*)alloc2((size_t)N_EDGES * sizeof(int));
    int*    rowp    = (int*)alloc2((size_t)(N_NODES + 1) * sizeof(int));
    int*    counts  = (int*)alloc2((size_t)PLACE_BLOCKS * N_WIN * sizeof(int));
    int*    colsum  = (int*)alloc2((size_t)N_WIN * sizeof(int));
    int*    gstart  = (int*)alloc2((size_t)(N_GRAPHS + 1) * sizeof(int));
    float*  pooled  = (float*)alloc2((size_t)N_GRAPHS * HIDDEN * N_LAYERS * sizeof(float));

    // fused prep + edge count
    prep_count_kernel<<<PREPC_BLOCKS, 256, 0, stream>>>(X, qA, w1all, w2all,
                                                        wt1, wt2, batch, gstart,
                                                        dst, counts);
    // place (absorbs column scan) -> fused per-window csr
    win_place_kernel<<<PLACE_BLOCKS, 512, 0, stream>>>(src, dst, counts, colsum, wedge);
    win_csr_kernel<<<N_WIN, 512, 0, stream>>>(wedge, colsum, rowp, csr);

    unsigned char* qin  = qA;
    unsigned char* qout = qB;
    __half* hcur = nullptr;
    for (int l = 0; l < N_LAYERS; ++l) {
        __half* hnext = (l & 1) ? hA : hB;
        const bool emit = (l < N_LAYERS - 1);
        const int grid = GM_BLOCKS + ((l > 0) ? POOL_BLKS : 0);
        gather_mlp_kernel<<<grid, 512, 0, stream>>>(
            qin, hcur, rowp, csr,
            wt1 + (size_t)l * HIDDEN * HIDDEN,
            wt2 + (size_t)l * HIDDEN * HIDDEN,
            b1all + (size_t)l * HIDDEN,
            b2all + (size_t)l * HIDDEN,
            gstart, pooled, l - 1,
            hnext, emit ? qout : (unsigned char*)nullptr);
        hcur = hnext;
        unsigned char* tmp = qin; qin = qout; qout = tmp;
    }

    // fused final pooling (layer 2, LDS-resident) + classifier head
    gpool_cls_kernel<<<N_GRAPHS, 256, 0, stream>>>(hcur, gstart, pooled,
                                                   cw1, cb1, cw2, cb2, cw3, cb3, out);
}

// Round 16
// 426.647 us; speedup vs baseline: 1.2210x; 1.2210x over previous
//
#include <hip/hip_runtime.h>
#include <hip/hip_fp16.h>
#include <cstddef>
#include <cstdint>

#define N_NODES   100000
#define N_EDGES   1600000
#define N_GRAPHS  512
#define HIDDEN    128
#define N_LAYERS  3

// 400-way counting sort. counts layout TRANSPOSED (R13): [win][block] so
// win_place can derive its own offsets with coalesced-ish column sums.
#define N_WIN        400
#define WIN_NODES    (N_NODES / N_WIN)      // 250
#define PLACE_BLOCKS 128
#define PCHUNK       (N_EDGES / PLACE_BLOCKS)  // 12500, divisible by 4

#define F2H_BLOCKS   ((N_NODES * HIDDEN / 8) / 256)            // 6250
#define WCONV_BLOCKS (N_LAYERS * 2 * 16)                       // 96
#define GB_BLOCKS    2                                         // graph-boundary search
// fused prep+count grid: count blocks FIRST, then f2h / wconv / gsearch
#define PREPC_BLOCKS (PLACE_BLOCKS + F2H_BLOCKS + WCONV_BLOCKS + GB_BLOCKS)

typedef _Float16 half8  __attribute__((ext_vector_type(8)));
typedef _Float16 half4v __attribute__((ext_vector_type(4)));
typedef _Float16 half2v __attribute__((ext_vector_type(2)));
typedef float    float8 __attribute__((ext_vector_type(8)));
typedef float    floatx4 __attribute__((ext_vector_type(4)));
typedef float    floatx2 __attribute__((ext_vector_type(2)));

// ---------------------------------------------------------------------------
// fused prep + win_count (R13-confirmed structure). R14: the f2h section now
// emits ONLY the fp8 twin (hA fp16 copy of X deleted -- gather's self-feature
// comes from the fp8 row too, so nothing reads fp16 X anymore): -25.6 MB.
// ---------------------------------------------------------------------------
__global__ __launch_bounds__(256) void prep_count_kernel(const float* __restrict__ X,
                                                         unsigned char* __restrict__ outq,
                                                         const float* __restrict__ w1,
                                                         const float* __restrict__ w2,
                                                         __half* __restrict__ wt1,
                                                         __half* __restrict__ wt2,
                                                         const int* __restrict__ batch,
                                                         int* __restrict__ gstart,
                                                         const int* __restrict__ dst,
                                                         int* __restrict__ counts) {
    __shared__ float tile[32][33];
    __shared__ int   cs[N_WIN];
    const int b = blockIdx.x;
    if (b < PLACE_BLOCKS) {
        for (int i = threadIdx.x; i < N_WIN; i += 256) cs[i] = 0;
        __syncthreads();
        const int4* d4 = (const int4*)(dst + b * PCHUNK);
        for (int i = threadIdx.x; i < PCHUNK / 4; i += 256) {
            int4 d = d4[i];
            atomicAdd(&cs[d.x / WIN_NODES], 1);
            atomicAdd(&cs[d.y / WIN_NODES], 1);
            atomicAdd(&cs[d.z / WIN_NODES], 1);
            atomicAdd(&cs[d.w / WIN_NODES], 1);
        }
        __syncthreads();
        for (int i = threadIdx.x; i < N_WIN; i += 256)
            counts[i * PLACE_BLOCKS + b] = cs[i];
    } else if (b < PLACE_BLOCKS + F2H_BLOCKS) {
        int t = (b - PLACE_BLOCKS) * 256 + threadIdx.x;
        const float4* in4 = (const float4*)X;
        float4 a = in4[t * 2 + 0];
        float4 c = in4[t * 2 + 1];
        unsigned r0 = 0, r1 = 0;
        r0 = __builtin_amdgcn_cvt_pk_fp8_f32(a.x, a.y, r0, false);
        r0 = __builtin_amdgcn_cvt_pk_fp8_f32(a.z, a.w, r0, true);
        r1 = __builtin_amdgcn_cvt_pk_fp8_f32(c.x, c.y, r1, false);
        r1 = __builtin_amdgcn_cvt_pk_fp8_f32(c.z, c.w, r1, true);
        ((uint2*)outq)[t] = make_uint2(r0, r1);
    } else if (b < PLACE_BLOCKS + F2H_BLOCKS + WCONV_BLOCKS) {
        const int bb = b - PLACE_BLOCKS - F2H_BLOCKS;
        const int mat = bb & 1;
        const int tt = (bb >> 1) & 15;
        const int l  = bb >> 5;
        const int ti = (tt >> 2) * 32, tj = (tt & 3) * 32;
        const float* W = (mat ? w2 : w1) + (size_t)l * HIDDEN * HIDDEN;
        __half* WT = (mat ? wt2 : wt1) + (size_t)l * HIDDEN * HIDDEN;
        const int r = threadIdx.x >> 5;
        const int c = threadIdx.x & 31;
#pragma unroll
        for (int rr = 0; rr < 4; ++rr)
            tile[r + 8 * rr][c] = W[(size_t)(ti + r + 8 * rr) * HIDDEN + tj + c];
        __syncthreads();
#pragma unroll
        for (int rr = 0; rr < 4; ++rr)
            WT[(size_t)(tj + r + 8 * rr) * HIDDEN + ti + c] =
                __float2half(tile[c][r + 8 * rr]);
    } else {
        // graph-boundary search: gstart[g] = lower_bound(batch, g)
        const int g = (b - PLACE_BLOCKS - F2H_BLOCKS - WCONV_BLOCKS) * 256 + threadIdx.x;
        if (g < N_GRAPHS) {
            int lo = 0, hi = N_NODES;
            while (lo < hi) {
                int mid = (lo + hi) >> 1;
                if (batch[mid] < g) lo = mid + 1; else hi = mid;
            }
            gstart[g] = lo;
        }
        if (g == 0) gstart[N_GRAPHS] = N_NODES;
    }
}

// place (R13-confirmed: absorbs win_scan1): each block derives its own
// per-window offsets from the transposed counts[w][b].
__global__ __launch_bounds__(512) void win_place_kernel(const int* __restrict__ src,
                                                        const int* __restrict__ dst,
                                                        const int* __restrict__ counts,
                                                        int* __restrict__ colsum,
                                                        int2* __restrict__ wedge) {
    __shared__ int ws[512];
    __shared__ int off[N_WIN];
    const int t = threadIdx.x;
    const int b = blockIdx.x;

    int total = 0, part = 0;
    if (t < N_WIN) {
        const int* col = counts + t * PLACE_BLOCKS;
#pragma unroll 4
        for (int bb = 0; bb < PLACE_BLOCKS; ++bb) {
            int v = col[bb];
            total += v;
            if (bb < b) part += v;
        }
        if (b == 0) colsum[t] = total;
    }
    ws[t] = (t < N_WIN) ? total : 0;
    __syncthreads();
#pragma unroll
    for (int o = 1; o < 512; o <<= 1) {
        int u = (t >= o) ? ws[t - o] : 0;
        __syncthreads();
        ws[t] += u;
        __syncthreads();
    }
    if (t < N_WIN) off[t] = part + ((t == 0) ? 0 : ws[t - 1]);
    __syncthreads();
    const int4* d4 = (const int4*)(dst + b * PCHUNK);
    const int4* s4 = (const int4*)(src + b * PCHUNK);
    for (int i = t; i < PCHUNK / 4; i += 512) {
        int4 d = d4[i];
        int4 s = s4[i];
        int p0 = atomicAdd(&off[d.x / WIN_NODES], 1); wedge[p0] = make_int2(d.x, s.x);
        int p1 = atomicAdd(&off[d.y / WIN_NODES], 1); wedge[p1] = make_int2(d.y, s.y);
        int p2 = atomicAdd(&off[d.z / WIN_NODES], 1); wedge[p2] = make_int2(d.z, s.z);
        int p3 = atomicAdd(&off[d.w / WIN_NODES], 1); wedge[p3] = make_int2(d.w, s.w);
    }
}

// fused per-window CSR: winbase scan -> count -> scan -> row_ptr -> scatter
__global__ __launch_bounds__(512) void win_csr_kernel(const int2* __restrict__ wedge,
                                                      const int* __restrict__ colsum,
                                                      int* __restrict__ row_ptr,
                                                      int* __restrict__ csr_src) {
    __shared__ int ws[512];
    __shared__ int cnt[WIN_NODES];
    __shared__ int bb[2];
    const int w = blockIdx.x, n0 = w * WIN_NODES, t = threadIdx.x;
    ws[t] = (t < N_WIN) ? colsum[t] : 0;
    __syncthreads();
#pragma unroll
    for (int o = 1; o < 512; o <<= 1) {
        int u = (t >= o) ? ws[t - o] : 0;
        __syncthreads();
        ws[t] += u;
        __syncthreads();
    }
    if (t == 0) { bb[0] = (w > 0) ? ws[w - 1] : 0; bb[1] = ws[w]; }
    if (w == N_WIN - 1 && t == 0) row_ptr[N_NODES] = ws[N_WIN - 1];
    for (int i = t; i < WIN_NODES; i += 512) cnt[i] = 0;
    __syncthreads();
    const int b0 = bb[0], b1 = bb[1];
    for (int e = b0 + t; e < b1; e += 512)
        atomicAdd(&cnt[wedge[e].x - n0], 1);
    __syncthreads();
    ws[t] = (t < WIN_NODES) ? cnt[t] : 0;
    __syncthreads();
#pragma unroll
    for (int o = 1; o < 512; o <<= 1) {
        int u = (t >= o) ? ws[t - o] : 0;
        __syncthreads();
        ws[t] += u;
        __syncthreads();
    }
    const int excl = (t == 0) ? 0 : ws[t - 1];
    if (t < WIN_NODES) {
        row_ptr[n0 + t] = b0 + excl;
        cnt[t] = b0 + excl;
    }
    __syncthreads();
    for (int e = b0 + t; e < b1; e += 512) {
        int2 ed = wedge[e];
        int p = atomicAdd(&cnt[ed.x - n0], 1);
        csr_src[p] = ed.y;
    }
}

// ---------------------------------------------------------------------------
// GIN aggregation. R14: (a) packed floatx2 accumulators -> v_pk_add_f32
// (24 -> 16 VALU ops per 16B); (b) self-feature folded in as one extra fp8
// "neighbor" on lane-group 0 (replaces the 25.6 MB/layer fp16 Xh read).
// ---------------------------------------------------------------------------
__device__ __forceinline__ void acc_fp8x16(floatx2* acc, uint4 v) {
    acc[0] += __builtin_amdgcn_cvt_pk_f32_fp8(v.x, false);
    acc[1] += __builtin_amdgcn_cvt_pk_f32_fp8(v.x, true);
    acc[2] += __builtin_amdgcn_cvt_pk_f32_fp8(v.y, false);
    acc[3] += __builtin_amdgcn_cvt_pk_f32_fp8(v.y, true);
    acc[4] += __builtin_amdgcn_cvt_pk_f32_fp8(v.z, false);
    acc[5] += __builtin_amdgcn_cvt_pk_f32_fp8(v.z, true);
    acc[6] += __builtin_amdgcn_cvt_pk_f32_fp8(v.w, false);
    acc[7] += __builtin_amdgcn_cvt_pk_f32_fp8(v.w, true);
}

__device__ __forceinline__ void gather_body(int wave, int lane,
                                            const unsigned char* __restrict__ Xq,
                                            __half* __restrict__ Zh,
                                            const int* __restrict__ row_ptr,
                                            const int* __restrict__ csr_src) {
    const int grp = lane >> 3;     // 0..7
    const int m   = lane & 7;      // 0..7
    const uint4* Q = (const uint4*)Xq;   // row = 8 x uint4 (128B)

    floatx2 acc[8];
#pragma unroll
    for (int j = 0; j < 8; ++j) acc[j] = floatx2{0.f, 0.f};

    // self feature (fp8 row): grp 0 adds its own row as one extra neighbor;
    // the butterfly sums it into every lane's total exactly once.
    if (grp == 0) {
        uint4 v = Q[(size_t)wave * 8 + m];
        acc_fp8x16(acc, v);
    }

    int k = row_ptr[wave];
    const int end = row_ptr[wave + 1];

    for (; k + 16 <= end; k += 16) {
        int n0 = csr_src[k + grp];
        int n1 = csr_src[k + 8 + grp];
        uint4 v0 = Q[(size_t)n0 * 8 + m];
        uint4 v1 = Q[(size_t)n1 * 8 + m];
        acc_fp8x16(acc, v0);
        acc_fp8x16(acc, v1);
    }
    if (k + 8 <= end) {
        int n0 = csr_src[k + grp];
        uint4 v0 = Q[(size_t)n0 * 8 + m];
        acc_fp8x16(acc, v0);
        k += 8;
    }
    int rem = end - k;
    if (grp < rem) {
        int n0 = csr_src[k + grp];
        uint4 v0 = Q[(size_t)n0 * 8 + m];
        acc_fp8x16(acc, v0);
    }

    half2v hh[8];
#pragma unroll
    for (int j = 0; j < 8; ++j) {
        hh[j][0] = (_Float16)acc[j][0];
        hh[j][1] = (_Float16)acc[j][1];
    }
#pragma unroll
    for (int j = 0; j < 8; ++j) {
        int b = __shfl_xor(__builtin_bit_cast(int, hh[j]), 8);
        hh[j] = hh[j] + __builtin_bit_cast(half2v, b);
    }
#pragma unroll
    for (int j = 0; j < 8; ++j) {
        int b = __shfl_xor(__builtin_bit_cast(int, hh[j]), 16);
        hh[j] = hh[j] + __builtin_bit_cast(half2v, b);
    }
#pragma unroll
    for (int j = 0; j < 8; ++j) {
        int b = __shfl_xor(__builtin_bit_cast(int, hh[j]), 32);
        hh[j] = hh[j] + __builtin_bit_cast(half2v, b);
    }

    if (grp == 0) {
        half8 o0, o1;
#pragma unroll
        for (int j = 0; j < 4; ++j) {
            o0[2 * j] = hh[j][0]; o0[2 * j + 1] = hh[j][1];
        }
#pragma unroll
        for (int j = 0; j < 4; ++j) {
            o1[2 * j] = hh[4 + j][0]; o1[2 * j + 1] = hh[4 + j][1];
        }
        ((half8*)(Zh + (size_t)wave * HIDDEN + 16 * m))[0] = o0;
        ((half8*)(Zh + (size_t)wave * HIDDEN + 16 * m))[1] = o1;
    }
}

__global__ void gather_kernel(const unsigned char* __restrict__ Xq,
                              __half* __restrict__ Zh,
                              const int* __restrict__ row_ptr,
                              const int* __restrict__ csr_src) {
    int wave = (blockIdx.x * blockDim.x + threadIdx.x) >> 6;
    if (wave >= N_NODES) return;
    gather_body(wave, threadIdx.x & 63, Xq, Zh, row_ptr, csr_src);
}

// ---------------------------------------------------------------------------
// Atomic-free global pooling (R15-confirmed). One block per graph. Pools the
// fp16 mlp output (Hpool) -- precision of pooled sums kept at fp16 source.
// ---------------------------------------------------------------------------
__device__ __forceinline__ void gpool_body(int g,
                                           const __half* __restrict__ Hpool,
                                           const int* __restrict__ gstart,
                                           float* __restrict__ pooled, int layer) {
    __shared__ float red[16][16][8];   // 8 KiB
    const int f8 = threadIdx.x & 15;   // col group: cols f8*8 .. f8*8+7
    const int qt = threadIdx.x >> 4;   // row phase 0..15
    const int s = gstart[g], e = gstart[g + 1];

    float acc[8];
#pragma unroll
    for (int j = 0; j < 8; ++j) acc[j] = 0.f;

    for (int n = s + qt; n < e; n += 16) {
        half8 v = ((const half8*)(Hpool + (size_t)n * HIDDEN))[f8];
#pragma unroll
        for (int j = 0; j < 8; ++j) acc[j] += (float)v[j];
    }
#pragma unroll
    for (int j = 0; j < 8; ++j) red[qt][f8][j] = acc[j];
    __syncthreads();

    if (threadIdx.x < 128) {
        const int c = threadIdx.x;
        float sum = 0.f;
#pragma unroll
        for (int p = 0; p < 16; ++p) sum += red[p][c >> 3][c & 7];
        pooled[(size_t)g * (HIDDEN * N_LAYERS) + layer * HIDDEN + c] = sum;
    }
}

// gather(l) + gpool(l-1) grid-split fusion (R16-confirmed). Pool reads the
// fp16 layer-(l-1) output; gather reads its fp8 twin (qbuf).
#define POOL_BLKS N_GRAPHS   // 512
__global__ __launch_bounds__(256) void gather_pool_kernel(const unsigned char* __restrict__ Xq,
                                                          const __half* __restrict__ Hpool,
                                                          __half* __restrict__ Zh,
                                                          const int* __restrict__ row_ptr,
                                                          const int* __restrict__ csr_src,
                                                          const int* __restrict__ gstart,
                                                          float* __restrict__ pooled,
                                                          int prev_layer) {
    if (blockIdx.x < POOL_BLKS) {
        gpool_body(blockIdx.x, Hpool, gstart, pooled, prev_layer);
        return;
    }
    int wave = ((blockIdx.x - POOL_BLKS) * 256 + threadIdx.x) >> 6;
    if (wave >= N_NODES) return;
    gather_body(wave, threadIdx.x & 63, Xq, Zh, row_ptr, csr_src);
}

// ---------------------------------------------------------------------------
// Fused final gpool(layer 2) + classifier (R13-confirmed).
// ---------------------------------------------------------------------------
__global__ __launch_bounds__(256) void gpool_cls_kernel(const __half* __restrict__ Xh,
                                                        const int* __restrict__ gstart,
                                                        const float* __restrict__ pooled,
                                                        const float* __restrict__ w1,
                                                        const float* __restrict__ b1,
                                                        const float* __restrict__ w2,
                                                        const float* __restrict__ b2,
                                                        const float* __restrict__ w3,
                                                        const float* __restrict__ b3,
                                                        float* __restrict__ out) {
    __shared__ float red[16][16][8];        // 8 KiB
    __shared__ float hin[HIDDEN * N_LAYERS];
    __shared__ float h1v[HIDDEN];
    __shared__ float redc[HIDDEN];
    const int g   = blockIdx.x;
    const int tid = threadIdx.x;
    const int f8  = tid & 15;
    const int qt  = tid >> 4;
    const int s = gstart[g], e = gstart[g + 1];

    // layers 0,1 pooled from global (written by gather_pool fusions)
    for (int i = tid; i < 2 * HIDDEN; i += 256)
        hin[i] = pooled[(size_t)g * (HIDDEN * N_LAYERS) + i];

    // layer-2 pooling into LDS
    float acc[8];
#pragma unroll
    for (int j = 0; j < 8; ++j) acc[j] = 0.f;
    for (int n = s + qt; n < e; n += 16) {
        half8 v = ((const half8*)(Xh + (size_t)n * HIDDEN))[f8];
#pragma unroll
        for (int j = 0; j < 8; ++j) acc[j] += (float)v[j];
    }
#pragma unroll
    for (int j = 0; j < 8; ++j) red[qt][f8][j] = acc[j];
    __syncthreads();
    if (tid < 128) {
        float sum = 0.f;
#pragma unroll
        for (int p = 0; p < 16; ++p) sum += red[p][tid >> 3][tid & 7];
        hin[2 * HIDDEN + tid] = sum;
    }
    __syncthreads();

    // classifier head
    if (tid < 128) {
        float sacc = 0.f;
        for (int k = 0; k < HIDDEN * N_LAYERS; ++k)
            sacc += hin[k] * w1[(size_t)k * HIDDEN + tid];
        h1v[tid] = fmaxf(sacc + b1[tid], 0.f);
    }
    __syncthreads();
    if (tid < 128) {
        float s2 = 0.f;
        for (int k = 0; k < HIDDEN; ++k) s2 += h1v[k] * w2[(size_t)k * HIDDEN + tid];
        s2 = fmaxf(s2 + b2[tid], 0.f);
        redc[tid] = s2 * w3[tid];
    }
    __syncthreads();
    for (int off = 64; off > 0; off >>= 1) {
        if (tid < off) redc[tid] += redc[tid + off];
        __syncthreads();
    }
    if (tid == 0) out[g] = redc[0] + b3[0];
}

// ---------------------------------------------------------------------------
// Fused wave-split MLP (R12-proven: wave-split slices, raw barrier without
// vmcnt drain, depth-2 A prefetch, launch_bounds(512,4)).
// ---------------------------------------------------------------------------
#define MMF_BLOCKS 512
__global__ __launch_bounds__(512, 4) void mlp_ws_kernel(const __half* __restrict__ A,
                                                        const __half* __restrict__ Wt1,
                                                        const __half* __restrict__ Wt2,
                                                        const float* __restrict__ b1,
                                                        const float* __restrict__ b2,
                                                        __half* __restrict__ C16,
                                                        unsigned char* __restrict__ Q8) {
    __shared__ _Float16 hs[2][16][128];   // 8 KiB, XOR-swizzled 16B chunks

    const int tid  = threadIdx.x;
    const int wv   = tid >> 6;         // 0..7: owned ct (16 output cols)
    const int lane = tid & 63;
    const int m    = lane & 15;
    const int q    = lane >> 4;
    const int NTILES = N_NODES / 16;   // 6250

    // per-wave weight slices + biases (register-resident, 40 VGPRs)
    half8 wf1[4], wf2[4];
    float bl1[4], bl2[4];
    {
        const half8* W1row = (const half8*)(Wt1 + (size_t)(wv * 16 + m) * HIDDEN);
        const half8* W2row = (const half8*)(Wt2 + (size_t)(wv * 16 + m) * HIDDEN);
#pragma unroll
        for (int c = 0; c < 4; ++c) { wf1[c] = W1row[c * 4 + q]; wf2[c] = W2row[c * 4 + q]; }
#pragma unroll
        for (int r = 0; r < 4; ++r) {
            bl1[r] = b1[wv * 16 + q * 4 + r];
            bl2[r] = b2[wv * 16 + q * 4 + r];
        }
    }

    // h-store address (swizzled): chunk (2wv + (q>>1)) ^ m, half-chunk q&1
    _Float16* hwr0 = &hs[0][m][(((2 * wv + (q >> 1)) ^ m) << 3) + ((q & 1) << 2)];
    _Float16* hwr1 = &hs[1][m][(((2 * wv + (q >> 1)) ^ m) << 3) + ((q & 1) << 2)];
    const _Float16* hrd0 = &hs[0][m][0];
    const _Float16* hrd1 = &hs[1][m][0];

    // prime: load tile 0 (cur) and tile 1 (nxt)
    int t = blockIdx.x;
    half8 c0, c1, c2, c3, p0, p1, p2, p3;
    {
        const half8* Ar = (const half8*)(A + (size_t)(t * 16 + m) * HIDDEN);
        c0 = Ar[q]; c1 = Ar[4 + q]; c2 = Ar[8 + q]; c3 = Ar[12 + q];
    }
    if (t + MMF_BLOCKS < NTILES) {
        const half8* Ar = (const half8*)(A + (size_t)((t + MMF_BLOCKS) * 16 + m) * HIDDEN);
        p0 = Ar[q]; p1 = Ar[4 + q]; p2 = Ar[8 + q]; p3 = Ar[12 + q];
    }

    int buf = 0;
    while (true) {
        // issue far prefetch (t+2S) before any compute on cur
        const int t2 = t + 2 * MMF_BLOCKS;
        half8 f0, f1, f2, f3;
        if (t2 < NTILES) {
            const half8* Ar = (const half8*)(A + (size_t)(t2 * 16 + m) * HIDDEN);
            f0 = Ar[q]; f1 = Ar[4 + q]; f2 = Ar[8 + q]; f3 = Ar[12 + q];
        }

        // ---- mm1: h(:, wv-slice) = relu(z @ W1 + b1) -> swizzled LDS
        {
            floatx4 acc = {0.f, 0.f, 0.f, 0.f};
            acc = __builtin_amdgcn_mfma_f32_16x16x32_f16(wf1[0], c0, acc, 0, 0, 0);
            acc = __builtin_amdgcn_mfma_f32_16x16x32_f16(wf1[1], c1, acc, 0, 0, 0);
            acc = __builtin_amdgcn_mfma_f32_16x16x32_f16(wf1[2], c2, acc, 0, 0, 0);
            acc = __builtin_amdgcn_mfma_f32_16x16x32_f16(wf1[3], c3, acc, 0, 0, 0);
            half4v o;
#pragma unroll
            for (int r = 0; r < 4; ++r) o[r] = (_Float16)fmaxf(acc[r] + bl1[r], 0.f);
            *(half4v*)(buf ? hwr1 : hwr0) = o;
        }
        // raw barrier: ds_write visible (lgkmcnt(0)) WITHOUT draining vmcnt --
        // the in-flight A-prefetch survives the barrier.
        __builtin_amdgcn_sched_barrier(0);
        asm volatile("s_waitcnt lgkmcnt(0)" ::: "memory");
        __builtin_amdgcn_s_barrier();
        __builtin_amdgcn_sched_barrier(0);

        // ---- mm2: read full h row fragments (swizzled), compute wv-slice
        {
            const _Float16* hr = buf ? hrd1 : hrd0;
            half8 h0 = *(const half8*)(hr + (((0 + q) ^ m) << 3));
            half8 h1 = *(const half8*)(hr + (((4 + q) ^ m) << 3));
            half8 h2 = *(const half8*)(hr + (((8 + q) ^ m) << 3));
            half8 h3 = *(const half8*)(hr + (((12 + q) ^ m) << 3));
            floatx4 acc = {0.f, 0.f, 0.f, 0.f};
            acc = __builtin_amdgcn_mfma_f32_16x16x32_f16(wf2[0], h0, acc, 0, 0, 0);
            acc = __builtin_amdgcn_mfma_f32_16x16x32_f16(wf2[1], h1, acc, 0, 0, 0);
            acc = __builtin_amdgcn_mfma_f32_16x16x32_f16(wf2[2], h2, acc, 0, 0, 0);
            acc = __builtin_amdgcn_mfma_f32_16x16x32_f16(wf2[3], h3, acc, 0, 0, 0);
            float v0 = fmaxf(acc[0] + bl2[0], 0.f);
            float v1 = fmaxf(acc[1] + bl2[1], 0.f);
            float v2 = fmaxf(acc[2] + bl2[2], 0.f);
            float v3 = fmaxf(acc[3] + bl2[3], 0.f);
            const size_t base = (size_t)(t * 16 + m) * HIDDEN + wv * 16 + q * 4;
            half4v o;
            o[0] = (_Float16)v0; o[1] = (_Float16)v1;
            o[2] = (_Float16)v2; o[3] = (_Float16)v3;
            *(half4v*)(C16 + base) = o;
            if (Q8) {
                unsigned r0 = 0;
                r0 = __builtin_amdgcn_cvt_pk_fp8_f32(v0, v1, r0, false);
                r0 = __builtin_amdgcn_cvt_pk_fp8_f32(v2, v3, r0, true);
                *(unsigned*)(Q8 + base) = r0;
            }
        }

        if (t + MMF_BLOCKS >= NTILES) break;
        t += MMF_BLOCKS;
        c0 = p0; c1 = p1; c2 = p2; c3 = p3;
        p0 = f0; p1 = f1; p2 = f2; p3 = f3;
        buf ^= 1;
    }
}

// ---------------------------------------------------------------------------
extern "C" void kernel_launch(void* const* d_in, const int* in_sizes, int n_in,
                              void* d_out, int out_size, void* d_ws, size_t ws_size,
                              hipStream_t stream) {
    const float* X     = (const float*)d_in[0];
    const int*   ei    = (const int*)d_in[1];
    const int*   batch = (const int*)d_in[2];
    const float* w1all = (const float*)d_in[3];
    const float* b1all = (const float*)d_in[4];
    const float* w2all = (const float*)d_in[5];
    const float* b2all = (const float*)d_in[6];
    const float* cw1   = (const float*)d_in[7];
    const float* cb1   = (const float*)d_in[8];
    const float* cw2   = (const float*)d_in[9];
    const float* cb2   = (const float*)d_in[10];
    const float* cw3   = (const float*)d_in[11];
    const float* cb3   = (const float*)d_in[12];
    float* out = (float*)d_out;

    const int* src = ei;
    const int* dst = ei + N_EDGES;

    char* p = (char*)d_ws;
    auto alloc2 = [&](size_t bytes) {
        char* r = p;
        p += (bytes + 255) & ~(size_t)255;
        return r;
    };
    __half* hA      = (__half*)alloc2((size_t)N_NODES * HIDDEN * sizeof(__half));
    __half* hB      = (__half*)alloc2((size_t)N_NODES * HIDDEN * sizeof(__half));
    __half* zh      = (__half*)alloc2((size_t)N_NODES * HIDDEN * sizeof(__half));
    unsigned char* qbuf = (unsigned char*)alloc2((size_t)N_NODES * HIDDEN);
    __half* wt1     = (__half*)alloc2((size_t)N_LAYERS * HIDDEN * HIDDEN * sizeof(__half));
    __half* wt2     = (__half*)alloc2((size_t)N_LAYERS * HIDDEN * HIDDEN * sizeof(__half));
    int2*   wedge   = (int2*)alloc2((size_t)N_EDGES * sizeof(int2));
    int*    csr     = (int*)alloc2((size_t)N_EDGES * sizeof(int));
    int*    rowp    = (int*)alloc2((size_t)(N_NODES + 1) * sizeof(int));
    int*    counts  = (int*)alloc2((size_t)PLACE_BLOCKS * N_WIN * sizeof(int));
    int*    colsum  = (int*)alloc2((size_t)N_WIN * sizeof(int));
    int*    gstart  = (int*)alloc2((size_t)(N_GRAPHS + 1) * sizeof(int));
    float*  pooled  = (float*)alloc2((size_t)N_GRAPHS * HIDDEN * N_LAYERS * sizeof(float));

    // fused prep + edge count (independent work, one dispatch)
    prep_count_kernel<<<PREPC_BLOCKS, 256, 0, stream>>>(X, qbuf, w1all, w2all,
                                                        wt1, wt2, batch, gstart,
                                                        dst, counts);
    // place (absorbs column scan) -> fused per-window csr
    win_place_kernel<<<PLACE_BLOCKS, 512, 0, stream>>>(src, dst, counts, colsum, wedge);
    win_csr_kernel<<<N_WIN, 512, 0, stream>>>(wedge, colsum, rowp, csr);

    const int gat_grid = (N_NODES + 3) / 4;           // 25000

    __half* hcur = nullptr;   // fp16 layer output; layer-0 gather uses qbuf only
    for (int l = 0; l < N_LAYERS; ++l) {
        __half* hnext = (l & 1) ? hA : hB;
        const bool emit = (l < N_LAYERS - 1);
        if (l == 0) {
            gather_kernel<<<gat_grid, 256, 0, stream>>>(qbuf, zh, rowp, csr);
        } else {
            // gather(l) from qbuf (fp8 twin) + gpool(l-1) from hcur (fp16)
            gather_pool_kernel<<<gat_grid + POOL_BLKS, 256, 0, stream>>>(
                qbuf, hcur, zh, rowp, csr, gstart, pooled, l - 1);
        }
        mlp_ws_kernel<<<MMF_BLOCKS, 512, 0, stream>>>(zh,
                                                      wt1 + (size_t)l * HIDDEN * HIDDEN,
                                                      wt2 + (size_t)l * HIDDEN * HIDDEN,
                                                      b1all + (size_t)l * HIDDEN,
                                                      b2all + (size_t)l * HIDDEN,
                                                      hnext,
                                                      emit ? qbuf : (unsigned char*)nullptr);
        hcur = hnext;
    }

    // fused final pooling (layer 2, LDS-resident) + classifier head
    gpool_cls_kernel<<<N_GRAPHS, 256, 0, stream>>>(hcur, gstart, pooled,
                                                   cw1, cb1, cw2, cb2, cw3, cb3, out);
}